// Round 10
// baseline (593.446 us; speedup 1.0000x reference)
//
#include <hip/hip_runtime.h>

// 2-layer GCN, R10: CSR build replaced by deterministic 2-level partition:
//   count1 (per-block LDS stripe histogram + degree count, reads dst half once)
//   scanB  (one-block scan of 1024x8 bucket-major counts -> exact bases)
//   write1 (re-read edges, coalesced full-line staging writes, NO placement atomics)
//   fill2  (stripe-pinned: 1.6MB staging + 1.6MB colv + pos all L2-resident)
// Kills the ~10x colv partial-line writeback (R7-R9: WRITE 131-195MB for 12.8MB).
// Agg/GEMM unchanged from R8/R9 (passing, absmax 1.95e-3).

#define N_NODES 100000
#define STRIPE_SZ 12500  // 8 stripes exactly
#define NBLK 1024        // partition blocks

typedef __attribute__((ext_vector_type(8))) short short8;
typedef __attribute__((ext_vector_type(4))) float f32x4;

// ---------- bf16 helpers (RN-even) ----------
__device__ __forceinline__ unsigned short f2bf(float f) {
    union { float f; unsigned u; } c; c.f = f;
    unsigned r = (c.u + 0x7fffu + ((c.u >> 16) & 1u)) >> 16;
    return (unsigned short)r;
}
__device__ __forceinline__ float2 bfpair(unsigned u) {
    union { float f; unsigned u; } a, b;
    a.u = u << 16; b.u = u & 0xffff0000u;
    return make_float2(a.f, b.f);
}
__device__ __forceinline__ unsigned packbf(float a, float b) {
    return (unsigned)f2bf(a) | ((unsigned)f2bf(b) << 16);
}

// ---------- edge dtype detection (one wave) ----------
__global__ void detect64_k(const unsigned long long* __restrict__ ei, int* __restrict__ flag) {
    unsigned long long v = ei[threadIdx.x & 63];
    unsigned long long bad = __ballot(v >= (1ULL << 32));
    if (threadIdx.x == 0) *flag = (bad == 0ULL) ? 1 : 0;
}

__device__ __forceinline__ int edge_at(const void* ei, int is64, long long idx) {
    if (is64) return (int)((const long long*)ei)[idx];
    return ((const int*)ei)[idx];
}

__global__ void zero_k(int* __restrict__ p, int n) {
    int i = blockIdx.x * blockDim.x + threadIdx.x;
    if (i < n) p[i] = 0;
}

// ---------- pass 1: per-block stripe histogram + degree count ----------
__global__ __launch_bounds__(256) void count1_k(const void* __restrict__ ei,
                                                const int* __restrict__ flag,
                                                int* __restrict__ cnt,
                                                int* __restrict__ bhist, int E) {
    __shared__ int lh[8];
    int t = threadIdx.x;
    if (t < 8) lh[t] = 0;
    __syncthreads();
    int is64 = *flag;
    int C = (E + NBLK - 1) / NBLK;
    int lo = blockIdx.x * C;
    int hi = lo + C; if (hi > E) hi = E;
    for (int e = lo + t; e < hi; e += 256) {
        int d = edge_at(ei, is64, (long long)E + e);
        if ((unsigned)d < (unsigned)N_NODES) {
            atomicAdd(&cnt[d], 1);
            atomicAdd(&lh[d / STRIPE_SZ], 1);
        }
    }
    __syncthreads();
    if (t < 8) bhist[blockIdx.x * 8 + t] = lh[t];
}

// ---------- scanB: one block, exclusive scan of bucket-major [8][NBLK] counts ----------
__global__ __launch_bounds__(256) void scanB_k(const int* __restrict__ bhist,
                                               int* __restrict__ bbase,   // [8*NBLK] bucket-major
                                               int* __restrict__ bstart)  // [9]
{
    __shared__ int sm[256];
    int t = threadIdx.x;
    int v[32]; int loc = 0;
#pragma unroll
    for (int k = 0; k < 32; ++k) {
        int f = t * 32 + k;
        int b = f >> 10, i = f & 1023;
        v[k] = bhist[i * 8 + b];
        loc += v[k];
    }
    sm[t] = loc; __syncthreads();
    for (int off = 1; off < 256; off <<= 1) {
        int x = (t >= off) ? sm[t - off] : 0;
        __syncthreads();
        sm[t] += x;
        __syncthreads();
    }
    int run = sm[t] - loc;  // exclusive
    if (t == 255) bstart[8] = sm[255];
#pragma unroll
    for (int k = 0; k < 32; ++k) {
        int f = t * 32 + k;
        bbase[f] = run;
        if ((f & 1023) == 0) bstart[f >> 10] = run;
        run += v[k];
    }
}

// ---------- exclusive scan of degrees, 1024 elems/block ----------
__global__ void scan1_k(const int* __restrict__ cnt, int* __restrict__ partial,
                        int* __restrict__ bsum, int n) {
    __shared__ int sm[256];
    int t = threadIdx.x;
    int base = blockIdx.x * 1024 + t * 4;
    int v[4]; int loc = 0;
#pragma unroll
    for (int j = 0; j < 4; ++j) { v[j] = (base + j < n) ? cnt[base + j] : 0; loc += v[j]; }
    sm[t] = loc; __syncthreads();
    for (int off = 1; off < 256; off <<= 1) {
        int x = (t >= off) ? sm[t - off] : 0;
        __syncthreads();
        sm[t] += x;
        __syncthreads();
    }
    int incl = sm[t];
    int run = incl - loc;
    if (t == 255) bsum[blockIdx.x] = incl;
#pragma unroll
    for (int j = 0; j < 4; ++j) {
        if (base + j < n) partial[base + j] = run;
        run += v[j];
    }
}

__global__ void scan2_k(int* __restrict__ bsum, int nb) {
    __shared__ int sm[256];
    int t = threadIdx.x;
    int v = (t < nb) ? bsum[t] : 0;
    sm[t] = v; __syncthreads();
    for (int off = 1; off < 256; off <<= 1) {
        int x = (t >= off) ? sm[t - off] : 0;
        __syncthreads();
        sm[t] += x;
        __syncthreads();
    }
    if (t < nb) bsum[t] = sm[t] - v;
}

__global__ void scan3_k(const int* __restrict__ bsum, const int* __restrict__ cnt,
                        int* __restrict__ row_ptr, int* __restrict__ pos,
                        float* __restrict__ dinv, int n) {
    int base = blockIdx.x * 1024 + threadIdx.x * 4;
    int add = bsum[blockIdx.x];
#pragma unroll
    for (int j = 0; j < 4; ++j) {
        int i = base + j;
        if (i < n) {
            int r = row_ptr[i] + add;
            row_ptr[i] = r;
            pos[i] = r;
            dinv[i] = rsqrtf((float)(cnt[i] + 1));  // +1 self-loop
        }
    }
}

// ---------- pass 2: deterministic staging write (src | dlocal<<17) ----------
__global__ __launch_bounds__(256) void write1_k(const void* __restrict__ ei,
                                                const int* __restrict__ flag,
                                                const int* __restrict__ bbase,
                                                unsigned* __restrict__ pairs, int E) {
    __shared__ int lofs[8];
    int t = threadIdx.x;
    if (t < 8) lofs[t] = bbase[t * NBLK + blockIdx.x];
    __syncthreads();
    int is64 = *flag;
    int C = (E + NBLK - 1) / NBLK;
    int lo = blockIdx.x * C;
    int hi = lo + C; if (hi > E) hi = E;
    for (int e = lo + t; e < hi; e += 256) {
        int s = edge_at(ei, is64, e);
        int d = edge_at(ei, is64, (long long)E + e);
        if ((unsigned)s >= (unsigned)N_NODES || (unsigned)d >= (unsigned)N_NODES) continue;
        int b = d / STRIPE_SZ;
        unsigned dl = (unsigned)(d - b * STRIPE_SZ);
        int p = atomicAdd(&lofs[b], 1);  // LDS atomic; fronts are contiguous -> full lines
        pairs[p] = (unsigned)s | (dl << 17);
    }
}

// ---------- pass 3: stripe-pinned CSR scatter, everything L2-resident ----------
__global__ __launch_bounds__(256) void fill2_k(const unsigned* __restrict__ pairs,
                                               const int* __restrict__ bstart,
                                               int* __restrict__ pos,
                                               int* __restrict__ colv) {
    int st = blockIdx.x & 7;
    int j = blockIdx.x >> 3;
    int NB = gridDim.x >> 3;
    int lo = bstart[st], hi = bstart[st + 1];
    int dbase = st * STRIPE_SZ;
    for (int i = lo + j * 256 + threadIdx.x; i < hi; i += NB * 256) {
        unsigned p = __builtin_nontemporal_load(pairs + i);
        int s = (int)(p & 0x1FFFFu);
        int d = dbase + (int)(p >> 17);
        int slot = atomicAdd(&pos[d], 1);
        colv[slot] = s;
    }
}

// ---------- weight prep: W^T in bf16 ----------
__global__ void prep_w_k(const float* __restrict__ W1, const float* __restrict__ W2,
                         unsigned short* __restrict__ w1bf, unsigned short* __restrict__ w2bf) {
    int i = blockIdx.x * 256 + threadIdx.x;
    if (i < 128 * 128) { int k = i >> 7, f = i & 127; w1bf[f * 128 + k] = f2bf(W1[i]); }
    if (i < 128 * 64)  { int k = i >> 6, f = i & 63;  w2bf[f * 128 + k] = f2bf(W2[i]); }
}

// ---------- GEMM1 (MFMA): h1[n][128] bf16 node-major = x @ W1 ----------
__global__ __launch_bounds__(256) void gemm1_k(const float* __restrict__ x,
                                               const unsigned short* __restrict__ w1bf,
                                               unsigned* __restrict__ h1, int Nn) {
    __shared__ __align__(16) unsigned short sA[128][136];  // W1^T [feat][k]
    __shared__ __align__(16) unsigned short sB[64][136];   // x [node][k] bf16
    int tid = threadIdx.x;
    int n0g = blockIdx.x * 64;
    {
        const uint4* src = (const uint4*)w1bf;
#pragma unroll
        for (int l = 0; l < 8; ++l) {
            int idx = tid + l * 256;
            int f = idx >> 4, kq = idx & 15;
            *(uint4*)&sA[f][kq * 8] = src[idx];
        }
    }
    {
        int n = tid >> 2, kq = tid & 3;
        int gn = n0g + n; if (gn >= Nn) gn = Nn - 1;
        const float4* xr = (const float4*)(x + (size_t)gn * 128 + kq * 32);
        unsigned short* dst = &sB[n][kq * 32];
#pragma unroll
        for (int i = 0; i < 8; ++i) {
            float4 v = xr[i];
            dst[i * 4 + 0] = f2bf(v.x); dst[i * 4 + 1] = f2bf(v.y);
            dst[i * 4 + 2] = f2bf(v.z); dst[i * 4 + 3] = f2bf(v.w);
        }
    }
    __syncthreads();
    int wave = tid >> 6, lane = tid & 63;
    int quad = lane >> 4, l16 = lane & 15;
    f32x4 z = {0.f, 0.f, 0.f, 0.f};
    f32x4 acc[8];
#pragma unroll
    for (int t = 0; t < 8; ++t) acc[t] = z;
#pragma unroll
    for (int kk = 0; kk < 4; ++kk) {
        int kb = kk * 32 + quad * 8;
        short8 a = *(const short8*)&sB[wave * 16 + l16][kb];
#pragma unroll
        for (int ft = 0; ft < 8; ++ft) {
            short8 b = *(const short8*)&sA[ft * 16 + l16][kb];
            acc[ft] = __builtin_amdgcn_mfma_f32_16x16x32_bf16(a, b, acc[ft], 0, 0, 0);
        }
    }
    __syncthreads();  // reuse sA as transpose buffer
    unsigned short (*sC)[136] = sA;
#pragma unroll
    for (int ft = 0; ft < 8; ++ft)
#pragma unroll
        for (int r = 0; r < 4; ++r)
            sC[wave * 16 + quad * 4 + r][ft * 16 + l16] = f2bf(acc[ft][r]);
    __syncthreads();
#pragma unroll
    for (int l = 0; l < 4; ++l) {
        int idx = tid + l * 256;
        int row = idx >> 4, q = idx & 15;
        int gn = n0g + row;
        if (gn < Nn)
            *(uint4*)&h1[(size_t)gn * 64 + q * 4] = *(uint4*)&sC[row][q * 8];
    }
}

// ---------- GEMM2 (MFMA): h2[n][64] bf16 node-major = hr @ W2 ----------
__global__ __launch_bounds__(256) void gemm2_k(const unsigned* __restrict__ hr,
                                               const unsigned short* __restrict__ w2bf,
                                               unsigned* __restrict__ h2, int Nn) {
    __shared__ __align__(16) unsigned short sA[64][136];
    __shared__ __align__(16) unsigned short sB[64][136];
    int tid = threadIdx.x;
    int n0g = blockIdx.x * 64;
    {
        const uint4* src = (const uint4*)w2bf;
#pragma unroll
        for (int l = 0; l < 4; ++l) {
            int idx = tid + l * 256;
            int f = idx >> 4, kq = idx & 15;
            *(uint4*)&sA[f][kq * 8] = src[idx];
        }
    }
    {
        const uint4* src = (const uint4*)hr;
#pragma unroll
        for (int l = 0; l < 4; ++l) {
            int idx = tid + l * 256;
            int row = idx >> 4, q = idx & 15;
            int gn = n0g + row; if (gn >= Nn) gn = Nn - 1;
            *(uint4*)&sB[row][q * 8] = src[(size_t)gn * 16 + q];
        }
    }
    __syncthreads();
    int wave = tid >> 6, lane = tid & 63;
    int quad = lane >> 4, l16 = lane & 15;
    f32x4 z = {0.f, 0.f, 0.f, 0.f};
    f32x4 acc[4];
#pragma unroll
    for (int t = 0; t < 4; ++t) acc[t] = z;
#pragma unroll
    for (int kk = 0; kk < 4; ++kk) {
        int kb = kk * 32 + quad * 8;
        short8 a = *(const short8*)&sB[wave * 16 + l16][kb];
#pragma unroll
        for (int ft = 0; ft < 4; ++ft) {
            short8 b = *(const short8*)&sA[ft * 16 + l16][kb];
            acc[ft] = __builtin_amdgcn_mfma_f32_16x16x32_bf16(a, b, acc[ft], 0, 0, 0);
        }
    }
    __syncthreads();
    unsigned short (*sC)[136] = sA;
#pragma unroll
    for (int ft = 0; ft < 4; ++ft)
#pragma unroll
        for (int r = 0; r < 4; ++r)
            sC[wave * 16 + quad * 4 + r][ft * 16 + l16] = f2bf(acc[ft][r]);
    __syncthreads();
#pragma unroll
    for (int l = 0; l < 2; ++l) {
        int idx = tid + l * 256;
        int row = idx >> 3, q = idx & 7;
        int gn = n0g + row;
        if (gn < Nn)
            *(uint4*)&h2[(size_t)gn * 32 + q * 4] = *(uint4*)&sC[row][q * 8];
    }
}

// ---------- agg1: wave=node, batched colv/dinv + shfl, 4-deep row-gather MLP ----------
__global__ __launch_bounds__(256) void agg1_k(const unsigned* __restrict__ h,
                                              const int* __restrict__ row_ptr,
                                              const int* __restrict__ cnt,
                                              const int* __restrict__ colv,
                                              const float* __restrict__ dinv,
                                              const float* __restrict__ bias,
                                              unsigned* __restrict__ out, int Nn, int E) {
    int node = blockIdx.x * 4 + (threadIdx.x >> 6);
    if (node >= Nn) return;
    int lane = threadIdx.x & 63;
    float di = dinv[node];
    int start = row_ptr[node];
    int deg = cnt[node];

    float2 hv = bfpair(h[(size_t)node * 64 + lane]);
    float w0 = di * di;
    float ax = w0 * hv.x, ay = w0 * hv.y;

    for (int base = 0; base < deg; base += 64) {
        int idx = base + lane;
        int ci = start + idx; if (ci >= E) ci = E - 1;
        int sl = colv[ci];
        float wl = (idx < deg) ? dinv[sl] : 0.f;
        int m = deg - base; if (m > 64) m = 64;
        int j = 0;
        for (; j + 4 <= m; j += 4) {
            int s0 = __shfl(sl, j),     s1 = __shfl(sl, j + 1);
            int s2 = __shfl(sl, j + 2), s3 = __shfl(sl, j + 3);
            float e0 = di * __shfl(wl, j),     e1 = di * __shfl(wl, j + 1);
            float e2 = di * __shfl(wl, j + 2), e3 = di * __shfl(wl, j + 3);
            unsigned u0 = h[(size_t)s0 * 64 + lane];
            unsigned u1 = h[(size_t)s1 * 64 + lane];
            unsigned u2 = h[(size_t)s2 * 64 + lane];
            unsigned u3 = h[(size_t)s3 * 64 + lane];
            float2 v0 = bfpair(u0), v1 = bfpair(u1), v2 = bfpair(u2), v3 = bfpair(u3);
            ax = fmaf(e0, v0.x, ax); ay = fmaf(e0, v0.y, ay);
            ax = fmaf(e1, v1.x, ax); ay = fmaf(e1, v1.y, ay);
            ax = fmaf(e2, v2.x, ax); ay = fmaf(e2, v2.y, ay);
            ax = fmaf(e3, v3.x, ax); ay = fmaf(e3, v3.y, ay);
        }
        for (; j < m; ++j) {
            int s = __shfl(sl, j);
            float we = di * __shfl(wl, j);
            float2 v = bfpair(h[(size_t)s * 64 + lane]);
            ax = fmaf(we, v.x, ax); ay = fmaf(we, v.y, ay);
        }
    }
    float r0 = fmaxf(ax + bias[lane * 2], 0.f);
    float r1 = fmaxf(ay + bias[lane * 2 + 1], 0.f);
    out[(size_t)node * 64 + lane] = packbf(r0, r1);
}

// ---------- agg2: wave=node, 2 edges per gather instruction ----------
__global__ __launch_bounds__(256) void agg2_k(const unsigned* __restrict__ h,
                                              const int* __restrict__ row_ptr,
                                              const int* __restrict__ cnt,
                                              const int* __restrict__ colv,
                                              const float* __restrict__ dinv,
                                              const float* __restrict__ bias,
                                              float* __restrict__ out, int Nn, int E) {
    int node = blockIdx.x * 4 + (threadIdx.x >> 6);
    if (node >= Nn) return;
    int lane = threadIdx.x & 63;
    int half = lane >> 5, fp = lane & 31;
    float di = dinv[node];
    int start = row_ptr[node];
    int deg = cnt[node];

    float2 hv = bfpair(h[(size_t)node * 32 + fp]);
    float w0 = (half == 0) ? di * di : 0.f;
    float ax = w0 * hv.x, ay = w0 * hv.y;

    for (int base = 0; base < deg; base += 64) {
        int idx = base + lane;
        int ci = start + idx; if (ci >= E) ci = E - 1;
        int sl = colv[ci];
        float wl = (idx < deg) ? dinv[sl] : 0.f;
        int m = deg - base; if (m > 64) m = 64;
        int j = 0;
        for (; j + 8 <= m; j += 8) {
            int q0 = j + half, q1 = j + 2 + half, q2 = j + 4 + half, q3 = j + 6 + half;
            int s0 = __shfl(sl, q0), s1 = __shfl(sl, q1);
            int s2 = __shfl(sl, q2), s3 = __shfl(sl, q3);
            float e0 = di * __shfl(wl, q0), e1 = di * __shfl(wl, q1);
            float e2 = di * __shfl(wl, q2), e3 = di * __shfl(wl, q3);
            unsigned u0 = h[(size_t)s0 * 32 + fp];
            unsigned u1 = h[(size_t)s1 * 32 + fp];
            unsigned u2 = h[(size_t)s2 * 32 + fp];
            unsigned u3 = h[(size_t)s3 * 32 + fp];
            float2 v0 = bfpair(u0), v1 = bfpair(u1), v2 = bfpair(u2), v3 = bfpair(u3);
            ax = fmaf(e0, v0.x, ax); ay = fmaf(e0, v0.y, ay);
            ax = fmaf(e1, v1.x, ax); ay = fmaf(e1, v1.y, ay);
            ax = fmaf(e2, v2.x, ax); ay = fmaf(e2, v2.y, ay);
            ax = fmaf(e3, v3.x, ax); ay = fmaf(e3, v3.y, ay);
        }
        for (; j < m; j += 2) {
            int q = j + half;
            int s = __shfl(sl, q & 63);
            float we = di * __shfl(wl, q & 63);
            float2 v = bfpair(h[(size_t)s * 32 + fp]);
            ax = fmaf(we, v.x, ax); ay = fmaf(we, v.y, ay);
        }
    }
    ax += __shfl_xor(ax, 32, 64);
    ay += __shfl_xor(ay, 32, 64);
    if (half == 0) {
        float2 r = make_float2(ax + bias[fp * 2], ay + bias[fp * 2 + 1]);
        *(float2*)&out[(size_t)node * 64 + fp * 2] = r;
    }
}

// ---------- launch ----------
extern "C" void kernel_launch(void* const* d_in, const int* in_sizes, int n_in,
                              void* d_out, int out_size, void* d_ws, size_t ws_size,
                              hipStream_t stream) {
    const float* x  = (const float*)d_in[0];
    const void*  ei = d_in[1];
    const float* W1 = (const float*)d_in[2];
    const float* b1 = (const float*)d_in[3];
    const float* W2 = (const float*)d_in[4];
    const float* b2 = (const float*)d_in[5];

    const int N = N_NODES;
    const int E = in_sizes[1] / 2;

    char* w = (char*)d_ws;
    size_t off = 0;
    auto take = [&](size_t bytes) {
        void* p = w + off;
        off = (off + bytes + 255) & ~(size_t)255;
        return p;
    };
    int*   flag    = (int*)take(sizeof(int));
    int*   cnt     = (int*)take((size_t)N * 4);
    int*   row_ptr = (int*)take((size_t)N * 4);
    int*   pos     = (int*)take((size_t)N * 4);
    int*   bsum    = (int*)take(128 * 4);
    int*   bhist   = (int*)take((size_t)NBLK * 8 * 4);
    int*   bbase   = (int*)take((size_t)NBLK * 8 * 4);
    int*   bstart  = (int*)take(16 * 4);
    float* dinv    = (float*)take((size_t)N * 4);
    unsigned* pairs = (unsigned*)take((size_t)E * 4);
    int*   colv    = (int*)take((size_t)E * 4);
    unsigned short* w1bf = (unsigned short*)take(128 * 128 * 2);
    unsigned short* w2bf = (unsigned short*)take(64 * 128 * 2);
    unsigned* hr   = (unsigned*)take((size_t)N * 64 * 4);   // bf16 [N][128]
    unsigned* h2   = (unsigned*)take((size_t)N * 32 * 4);   // bf16 [N][64]
    (void)ws_size; (void)n_in; (void)out_size;

    unsigned* h1 = (unsigned*)d_out;  // bf16 [N][128] in d_out, dead before agg2 writes

    const int nscan = (N + 1023) / 1024;  // 98

    detect64_k<<<1, 64, 0, stream>>>((const unsigned long long*)ei, flag);
    zero_k<<<(N + 255) / 256, 256, 0, stream>>>(cnt, N);
    count1_k<<<NBLK, 256, 0, stream>>>(ei, flag, cnt, bhist, E);
    scanB_k<<<1, 256, 0, stream>>>(bhist, bbase, bstart);
    scan1_k<<<nscan, 256, 0, stream>>>(cnt, row_ptr, bsum, N);
    scan2_k<<<1, 256, 0, stream>>>(bsum, nscan);
    scan3_k<<<nscan, 256, 0, stream>>>(bsum, cnt, row_ptr, pos, dinv, N);
    write1_k<<<NBLK, 256, 0, stream>>>(ei, flag, bbase, pairs, E);
    fill2_k<<<2048, 256, 0, stream>>>(pairs, bstart, pos, colv);
    prep_w_k<<<64, 256, 0, stream>>>(W1, W2, w1bf, w2bf);

    gemm1_k<<<(N + 63) / 64, 256, 0, stream>>>(x, w1bf, h1, N);
    agg1_k<<<(N + 3) / 4, 256, 0, stream>>>(h1, row_ptr, cnt, colv, dinv, b1, hr, N, E);
    gemm2_k<<<(N + 63) / 64, 256, 0, stream>>>(hr, w2bf, h2, N);
    agg2_k<<<(N + 3) / 4, 256, 0, stream>>>(h2, row_ptr, cnt, colv, dinv, b2, (float*)d_out, N, E);
}

// Round 11
// 519.344 us; speedup vs baseline: 1.1427x; 1.1427x over previous
//
#include <hip/hip_runtime.h>

// 2-layer GCN, R11: CSR build via single-level 391-bucket partition with
// block-private final scatter. R7-R10 lesson: ANY colv region written
// concurrently by many blocks gets ~10x partial-line writeback (non-coherent
// per-XCD L2s, byte-masked writebacks; blockIdx&7 is NOT a reliable XCD map).
// fill3 gives each bucket (256 dst nodes, ~32KB colv range) to exactly ONE
// block -> no line sharing -> amplification structurally impossible.
// Agg/GEMMs unchanged from R10 (passing, absmax 1.95e-3).

#define N_NODES 100000
#define NBLK  256   // partition blocks
#define NBUCK 391   // ceil(100000/256) buckets of 256 dst nodes

typedef __attribute__((ext_vector_type(8))) short short8;
typedef __attribute__((ext_vector_type(4))) float f32x4;

// ---------- bf16 helpers (RN-even) ----------
__device__ __forceinline__ unsigned short f2bf(float f) {
    union { float f; unsigned u; } c; c.f = f;
    unsigned r = (c.u + 0x7fffu + ((c.u >> 16) & 1u)) >> 16;
    return (unsigned short)r;
}
__device__ __forceinline__ float2 bfpair(unsigned u) {
    union { float f; unsigned u; } a, b;
    a.u = u << 16; b.u = u & 0xffff0000u;
    return make_float2(a.f, b.f);
}
__device__ __forceinline__ unsigned packbf(float a, float b) {
    return (unsigned)f2bf(a) | ((unsigned)f2bf(b) << 16);
}

// ---------- edge dtype detection (one wave) ----------
__global__ void detect64_k(const unsigned long long* __restrict__ ei, int* __restrict__ flag) {
    unsigned long long v = ei[threadIdx.x & 63];
    unsigned long long bad = __ballot(v >= (1ULL << 32));
    if (threadIdx.x == 0) *flag = (bad == 0ULL) ? 1 : 0;
}

__device__ __forceinline__ int edge_at(const void* ei, int is64, long long idx) {
    if (is64) return (int)((const long long*)ei)[idx];
    return ((const int*)ei)[idx];
}

__global__ void zero_k(int* __restrict__ p, int n) {
    int i = blockIdx.x * blockDim.x + threadIdx.x;
    if (i < n) p[i] = 0;
}

// ---------- pass 1: per-block 391-bucket LDS histogram + degree count ----------
__global__ __launch_bounds__(256) void count1_k(const void* __restrict__ ei,
                                                const int* __restrict__ flag,
                                                int* __restrict__ cnt,
                                                int* __restrict__ bhist, int E) {
    __shared__ int lh[NBUCK];
    int t = threadIdx.x;
    for (int i = t; i < NBUCK; i += 256) lh[i] = 0;
    __syncthreads();
    int is64 = *flag;
    int C = (E + NBLK - 1) / NBLK;
    int lo = blockIdx.x * C;
    int hi = lo + C; if (hi > E) hi = E;
    for (int e = lo + t; e < hi; e += 256) {
        int d = edge_at(ei, is64, (long long)E + e);
        if ((unsigned)d < (unsigned)N_NODES) {
            atomicAdd(&cnt[d], 1);
            atomicAdd(&lh[d >> 8], 1);
        }
    }
    __syncthreads();
    for (int i = t; i < NBUCK; i += 256) bhist[(size_t)i * NBLK + blockIdx.x] = lh[i];
}

// ---------- generic exclusive scan, 1024 elems/block ----------
__global__ void scan1_k(const int* __restrict__ cnt, int* __restrict__ partial,
                        int* __restrict__ bsum, int n) {
    __shared__ int sm[256];
    int t = threadIdx.x;
    int base = blockIdx.x * 1024 + t * 4;
    int v[4]; int loc = 0;
#pragma unroll
    for (int j = 0; j < 4; ++j) { v[j] = (base + j < n) ? cnt[base + j] : 0; loc += v[j]; }
    sm[t] = loc; __syncthreads();
    for (int off = 1; off < 256; off <<= 1) {
        int x = (t >= off) ? sm[t - off] : 0;
        __syncthreads();
        sm[t] += x;
        __syncthreads();
    }
    int incl = sm[t];
    int run = incl - loc;
    if (t == 255) bsum[blockIdx.x] = incl;
#pragma unroll
    for (int j = 0; j < 4; ++j) {
        if (base + j < n) partial[base + j] = run;
        run += v[j];
    }
}

__global__ void scan2_k(int* __restrict__ bsum, int nb) {
    __shared__ int sm[256];
    int t = threadIdx.x;
    int v = (t < nb) ? bsum[t] : 0;
    sm[t] = v; __syncthreads();
    for (int off = 1; off < 256; off <<= 1) {
        int x = (t >= off) ? sm[t - off] : 0;
        __syncthreads();
        sm[t] += x;
        __syncthreads();
    }
    if (t < nb) bsum[t] = sm[t] - v;
}

// finalize bucket-base scan in place; also emit total valid count
__global__ void scanadd_k(const int* __restrict__ bsum, int* __restrict__ arr,
                          const int* __restrict__ raw, int* __restrict__ tot, int n) {
    int base = blockIdx.x * 1024 + threadIdx.x * 4;
    int add = bsum[blockIdx.x];
#pragma unroll
    for (int j = 0; j < 4; ++j) {
        int i = base + j;
        if (i < n) {
            int v = arr[i] + add;
            arr[i] = v;
            if (i == n - 1) *tot = v + raw[i];
        }
    }
}

// finalize degree scan: row_ptr + dinv
__global__ void scan3_k(const int* __restrict__ bsum, const int* __restrict__ cnt,
                        int* __restrict__ row_ptr, float* __restrict__ dinv, int n) {
    int base = blockIdx.x * 1024 + threadIdx.x * 4;
    int add = bsum[blockIdx.x];
#pragma unroll
    for (int j = 0; j < 4; ++j) {
        int i = base + j;
        if (i < n) {
            row_ptr[i] += add;
            dinv[i] = rsqrtf((float)(cnt[i] + 1));  // +1 self-loop
        }
    }
}

// ---------- pass 2: deterministic staging write (src | dlocal<<17), full-line fronts ----------
__global__ __launch_bounds__(256) void write1_k(const void* __restrict__ ei,
                                                const int* __restrict__ flag,
                                                const int* __restrict__ bbase,
                                                unsigned* __restrict__ pairs, int E) {
    __shared__ int lofs[NBUCK];
    int t = threadIdx.x;
    for (int i = t; i < NBUCK; i += 256) lofs[i] = bbase[(size_t)i * NBLK + blockIdx.x];
    __syncthreads();
    int is64 = *flag;
    int C = (E + NBLK - 1) / NBLK;
    int lo = blockIdx.x * C;
    int hi = lo + C; if (hi > E) hi = E;
    for (int e = lo + t; e < hi; e += 256) {
        int s = edge_at(ei, is64, e);
        int d = edge_at(ei, is64, (long long)E + e);
        if ((unsigned)s >= (unsigned)N_NODES || (unsigned)d >= (unsigned)N_NODES) continue;
        int b = d >> 8;
        int p = atomicAdd(&lofs[b], 1);  // LDS atomic; per-block fronts are contiguous
        pairs[p] = (unsigned)s | ((unsigned)(d & 255) << 17);
    }
}

// ---------- pass 3: block-private scatter into exact CSR positions ----------
__global__ __launch_bounds__(256) void fill3_k(const unsigned* __restrict__ pairs,
                                               const int* __restrict__ bbase,
                                               const int* __restrict__ tot,
                                               const int* __restrict__ row_ptr,
                                               int* __restrict__ colv, int Nn) {
    __shared__ int cur[256];
    int b = blockIdx.x;
    int t = threadIdx.x;
    int n0 = b << 8;
    int nn = Nn - n0; if (nn > 256) nn = 256;
    if (t < nn) cur[t] = row_ptr[n0 + t];
    __syncthreads();
    int lo = bbase[(size_t)b * NBLK];
    int hi = (b == NBUCK - 1) ? *tot : bbase[((size_t)b + 1) * NBLK];
    for (int i = lo + t; i < hi; i += 256) {
        unsigned p = __builtin_nontemporal_load(pairs + i);
        int dl = (int)(p >> 17);
        int slot = atomicAdd(&cur[dl], 1);
        colv[slot] = (int)(p & 0x1FFFFu);   // block-private ~32KB range: no line sharing
    }
}

// ---------- weight prep: W^T in bf16 ----------
__global__ void prep_w_k(const float* __restrict__ W1, const float* __restrict__ W2,
                         unsigned short* __restrict__ w1bf, unsigned short* __restrict__ w2bf) {
    int i = blockIdx.x * 256 + threadIdx.x;
    if (i < 128 * 128) { int k = i >> 7, f = i & 127; w1bf[f * 128 + k] = f2bf(W1[i]); }
    if (i < 128 * 64)  { int k = i >> 6, f = i & 63;  w2bf[f * 128 + k] = f2bf(W2[i]); }
}

// ---------- GEMM1 (MFMA): h1[n][128] bf16 node-major = x @ W1 ----------
__global__ __launch_bounds__(256) void gemm1_k(const float* __restrict__ x,
                                               const unsigned short* __restrict__ w1bf,
                                               unsigned* __restrict__ h1, int Nn) {
    __shared__ __align__(16) unsigned short sA[128][136];  // W1^T [feat][k]
    __shared__ __align__(16) unsigned short sB[64][136];   // x [node][k] bf16
    int tid = threadIdx.x;
    int n0g = blockIdx.x * 64;
    {
        const uint4* src = (const uint4*)w1bf;
#pragma unroll
        for (int l = 0; l < 8; ++l) {
            int idx = tid + l * 256;
            int f = idx >> 4, kq = idx & 15;
            *(uint4*)&sA[f][kq * 8] = src[idx];
        }
    }
    {
        int n = tid >> 2, kq = tid & 3;
        int gn = n0g + n; if (gn >= Nn) gn = Nn - 1;
        const float4* xr = (const float4*)(x + (size_t)gn * 128 + kq * 32);
        unsigned short* dst = &sB[n][kq * 32];
#pragma unroll
        for (int i = 0; i < 8; ++i) {
            float4 v = xr[i];
            dst[i * 4 + 0] = f2bf(v.x); dst[i * 4 + 1] = f2bf(v.y);
            dst[i * 4 + 2] = f2bf(v.z); dst[i * 4 + 3] = f2bf(v.w);
        }
    }
    __syncthreads();
    int wave = tid >> 6, lane = tid & 63;
    int quad = lane >> 4, l16 = lane & 15;
    f32x4 z = {0.f, 0.f, 0.f, 0.f};
    f32x4 acc[8];
#pragma unroll
    for (int t = 0; t < 8; ++t) acc[t] = z;
#pragma unroll
    for (int kk = 0; kk < 4; ++kk) {
        int kb = kk * 32 + quad * 8;
        short8 a = *(const short8*)&sB[wave * 16 + l16][kb];
#pragma unroll
        for (int ft = 0; ft < 8; ++ft) {
            short8 b = *(const short8*)&sA[ft * 16 + l16][kb];
            acc[ft] = __builtin_amdgcn_mfma_f32_16x16x32_bf16(a, b, acc[ft], 0, 0, 0);
        }
    }
    __syncthreads();  // reuse sA as transpose buffer
    unsigned short (*sC)[136] = sA;
#pragma unroll
    for (int ft = 0; ft < 8; ++ft)
#pragma unroll
        for (int r = 0; r < 4; ++r)
            sC[wave * 16 + quad * 4 + r][ft * 16 + l16] = f2bf(acc[ft][r]);
    __syncthreads();
#pragma unroll
    for (int l = 0; l < 4; ++l) {
        int idx = tid + l * 256;
        int row = idx >> 4, q = idx & 15;
        int gn = n0g + row;
        if (gn < Nn)
            *(uint4*)&h1[(size_t)gn * 64 + q * 4] = *(uint4*)&sC[row][q * 8];
    }
}

// ---------- GEMM2 (MFMA): h2[n][64] bf16 node-major = hr @ W2 ----------
__global__ __launch_bounds__(256) void gemm2_k(const unsigned* __restrict__ hr,
                                               const unsigned short* __restrict__ w2bf,
                                               unsigned* __restrict__ h2, int Nn) {
    __shared__ __align__(16) unsigned short sA[64][136];
    __shared__ __align__(16) unsigned short sB[64][136];
    int tid = threadIdx.x;
    int n0g = blockIdx.x * 64;
    {
        const uint4* src = (const uint4*)w2bf;
#pragma unroll
        for (int l = 0; l < 4; ++l) {
            int idx = tid + l * 256;
            int f = idx >> 4, kq = idx & 15;
            *(uint4*)&sA[f][kq * 8] = src[idx];
        }
    }
    {
        const uint4* src = (const uint4*)hr;
#pragma unroll
        for (int l = 0; l < 4; ++l) {
            int idx = tid + l * 256;
            int row = idx >> 4, q = idx & 15;
            int gn = n0g + row; if (gn >= Nn) gn = Nn - 1;
            *(uint4*)&sB[row][q * 8] = src[(size_t)gn * 16 + q];
        }
    }
    __syncthreads();
    int wave = tid >> 6, lane = tid & 63;
    int quad = lane >> 4, l16 = lane & 15;
    f32x4 z = {0.f, 0.f, 0.f, 0.f};
    f32x4 acc[4];
#pragma unroll
    for (int t = 0; t < 4; ++t) acc[t] = z;
#pragma unroll
    for (int kk = 0; kk < 4; ++kk) {
        int kb = kk * 32 + quad * 8;
        short8 a = *(const short8*)&sB[wave * 16 + l16][kb];
#pragma unroll
        for (int ft = 0; ft < 4; ++ft) {
            short8 b = *(const short8*)&sA[ft * 16 + l16][kb];
            acc[ft] = __builtin_amdgcn_mfma_f32_16x16x32_bf16(a, b, acc[ft], 0, 0, 0);
        }
    }
    __syncthreads();
    unsigned short (*sC)[136] = sA;
#pragma unroll
    for (int ft = 0; ft < 4; ++ft)
#pragma unroll
        for (int r = 0; r < 4; ++r)
            sC[wave * 16 + quad * 4 + r][ft * 16 + l16] = f2bf(acc[ft][r]);
    __syncthreads();
#pragma unroll
    for (int l = 0; l < 2; ++l) {
        int idx = tid + l * 256;
        int row = idx >> 3, q = idx & 7;
        int gn = n0g + row;
        if (gn < Nn)
            *(uint4*)&h2[(size_t)gn * 32 + q * 4] = *(uint4*)&sC[row][q * 8];
    }
}

// ---------- agg1: wave=node, batched colv/dinv + shfl, 4-deep row-gather MLP ----------
__global__ __launch_bounds__(256) void agg1_k(const unsigned* __restrict__ h,
                                              const int* __restrict__ row_ptr,
                                              const int* __restrict__ cnt,
                                              const int* __restrict__ colv,
                                              const float* __restrict__ dinv,
                                              const float* __restrict__ bias,
                                              unsigned* __restrict__ out, int Nn, int E) {
    int node = blockIdx.x * 4 + (threadIdx.x >> 6);
    if (node >= Nn) return;
    int lane = threadIdx.x & 63;
    float di = dinv[node];
    int start = row_ptr[node];
    int deg = cnt[node];

    float2 hv = bfpair(h[(size_t)node * 64 + lane]);
    float w0 = di * di;
    float ax = w0 * hv.x, ay = w0 * hv.y;

    for (int base = 0; base < deg; base += 64) {
        int idx = base + lane;
        int ci = start + idx; if (ci >= E) ci = E - 1;
        int sl = colv[ci];
        float wl = (idx < deg) ? dinv[sl] : 0.f;
        int m = deg - base; if (m > 64) m = 64;
        int j = 0;
        for (; j + 4 <= m; j += 4) {
            int s0 = __shfl(sl, j),     s1 = __shfl(sl, j + 1);
            int s2 = __shfl(sl, j + 2), s3 = __shfl(sl, j + 3);
            float e0 = di * __shfl(wl, j),     e1 = di * __shfl(wl, j + 1);
            float e2 = di * __shfl(wl, j + 2), e3 = di * __shfl(wl, j + 3);
            unsigned u0 = h[(size_t)s0 * 64 + lane];
            unsigned u1 = h[(size_t)s1 * 64 + lane];
            unsigned u2 = h[(size_t)s2 * 64 + lane];
            unsigned u3 = h[(size_t)s3 * 64 + lane];
            float2 v0 = bfpair(u0), v1 = bfpair(u1), v2 = bfpair(u2), v3 = bfpair(u3);
            ax = fmaf(e0, v0.x, ax); ay = fmaf(e0, v0.y, ay);
            ax = fmaf(e1, v1.x, ax); ay = fmaf(e1, v1.y, ay);
            ax = fmaf(e2, v2.x, ax); ay = fmaf(e2, v2.y, ay);
            ax = fmaf(e3, v3.x, ax); ay = fmaf(e3, v3.y, ay);
        }
        for (; j < m; ++j) {
            int s = __shfl(sl, j);
            float we = di * __shfl(wl, j);
            float2 v = bfpair(h[(size_t)s * 64 + lane]);
            ax = fmaf(we, v.x, ax); ay = fmaf(we, v.y, ay);
        }
    }
    float r0 = fmaxf(ax + bias[lane * 2], 0.f);
    float r1 = fmaxf(ay + bias[lane * 2 + 1], 0.f);
    out[(size_t)node * 64 + lane] = packbf(r0, r1);
}

// ---------- agg2: wave=node, 2 edges per gather instruction ----------
__global__ __launch_bounds__(256) void agg2_k(const unsigned* __restrict__ h,
                                              const int* __restrict__ row_ptr,
                                              const int* __restrict__ cnt,
                                              const int* __restrict__ colv,
                                              const float* __restrict__ dinv,
                                              const float* __restrict__ bias,
                                              float* __restrict__ out, int Nn, int E) {
    int node = blockIdx.x * 4 + (threadIdx.x >> 6);
    if (node >= Nn) return;
    int lane = threadIdx.x & 63;
    int half = lane >> 5, fp = lane & 31;
    float di = dinv[node];
    int start = row_ptr[node];
    int deg = cnt[node];

    float2 hv = bfpair(h[(size_t)node * 32 + fp]);
    float w0 = (half == 0) ? di * di : 0.f;
    float ax = w0 * hv.x, ay = w0 * hv.y;

    for (int base = 0; base < deg; base += 64) {
        int idx = base + lane;
        int ci = start + idx; if (ci >= E) ci = E - 1;
        int sl = colv[ci];
        float wl = (idx < deg) ? dinv[sl] : 0.f;
        int m = deg - base; if (m > 64) m = 64;
        int j = 0;
        for (; j + 8 <= m; j += 8) {
            int q0 = j + half, q1 = j + 2 + half, q2 = j + 4 + half, q3 = j + 6 + half;
            int s0 = __shfl(sl, q0), s1 = __shfl(sl, q1);
            int s2 = __shfl(sl, q2), s3 = __shfl(sl, q3);
            float e0 = di * __shfl(wl, q0), e1 = di * __shfl(wl, q1);
            float e2 = di * __shfl(wl, q2), e3 = di * __shfl(wl, q3);
            unsigned u0 = h[(size_t)s0 * 32 + fp];
            unsigned u1 = h[(size_t)s1 * 32 + fp];
            unsigned u2 = h[(size_t)s2 * 32 + fp];
            unsigned u3 = h[(size_t)s3 * 32 + fp];
            float2 v0 = bfpair(u0), v1 = bfpair(u1), v2 = bfpair(u2), v3 = bfpair(u3);
            ax = fmaf(e0, v0.x, ax); ay = fmaf(e0, v0.y, ay);
            ax = fmaf(e1, v1.x, ax); ay = fmaf(e1, v1.y, ay);
            ax = fmaf(e2, v2.x, ax); ay = fmaf(e2, v2.y, ay);
            ax = fmaf(e3, v3.x, ax); ay = fmaf(e3, v3.y, ay);
        }
        for (; j < m; j += 2) {
            int q = j + half;
            int s = __shfl(sl, q & 63);
            float we = di * __shfl(wl, q & 63);
            float2 v = bfpair(h[(size_t)s * 32 + fp]);
            ax = fmaf(we, v.x, ax); ay = fmaf(we, v.y, ay);
        }
    }
    ax += __shfl_xor(ax, 32, 64);
    ay += __shfl_xor(ay, 32, 64);
    if (half == 0) {
        float2 r = make_float2(ax + bias[fp * 2], ay + bias[fp * 2 + 1]);
        *(float2*)&out[(size_t)node * 64 + fp * 2] = r;
    }
}

// ---------- launch ----------
extern "C" void kernel_launch(void* const* d_in, const int* in_sizes, int n_in,
                              void* d_out, int out_size, void* d_ws, size_t ws_size,
                              hipStream_t stream) {
    const float* x  = (const float*)d_in[0];
    const void*  ei = d_in[1];
    const float* W1 = (const float*)d_in[2];
    const float* b1 = (const float*)d_in[3];
    const float* W2 = (const float*)d_in[4];
    const float* b2 = (const float*)d_in[5];

    const int N = N_NODES;
    const int E = in_sizes[1] / 2;
    const int NB = NBLK * NBUCK;  // 100096

    char* w = (char*)d_ws;
    size_t off = 0;
    auto take = [&](size_t bytes) {
        void* p = w + off;
        off = (off + bytes + 255) & ~(size_t)255;
        return p;
    };
    int*   flag    = (int*)take(2 * sizeof(int));
    int*   tot     = flag + 1;
    int*   cnt     = (int*)take((size_t)N * 4);
    int*   row_ptr = (int*)take((size_t)N * 4);
    int*   bsumA   = (int*)take(128 * 4);
    int*   bsumB   = (int*)take(128 * 4);
    int*   bhist   = (int*)take((size_t)NB * 4);
    int*   bbase   = (int*)take((size_t)NB * 4);
    float* dinv    = (float*)take((size_t)N * 4);
    unsigned* pairs = (unsigned*)take((size_t)E * 4);
    int*   colv    = (int*)take((size_t)E * 4);
    unsigned short* w1bf = (unsigned short*)take(128 * 128 * 2);
    unsigned short* w2bf = (unsigned short*)take(64 * 128 * 2);
    unsigned* hr   = (unsigned*)take((size_t)N * 64 * 4);   // bf16 [N][128]
    unsigned* h2   = (unsigned*)take((size_t)N * 32 * 4);   // bf16 [N][64]
    (void)ws_size; (void)n_in; (void)out_size;

    unsigned* h1 = (unsigned*)d_out;  // bf16 [N][128] in d_out, dead before agg2 writes

    const int nscanN = (N + 1023) / 1024;   // 98
    const int nscanB = (NB + 1023) / 1024;  // 98

    detect64_k<<<1, 64, 0, stream>>>((const unsigned long long*)ei, flag);
    zero_k<<<(N + 255) / 256, 256, 0, stream>>>(cnt, N);
    count1_k<<<NBLK, 256, 0, stream>>>(ei, flag, cnt, bhist, E);
    // bucket-base scan (exclusive over bucket-major [NBUCK][NBLK])
    scan1_k<<<nscanB, 256, 0, stream>>>(bhist, bbase, bsumB, NB);
    scan2_k<<<1, 256, 0, stream>>>(bsumB, nscanB);
    scanadd_k<<<nscanB, 256, 0, stream>>>(bsumB, bbase, bhist, tot, NB);
    // degree scan -> row_ptr, dinv
    scan1_k<<<nscanN, 256, 0, stream>>>(cnt, row_ptr, bsumA, N);
    scan2_k<<<1, 256, 0, stream>>>(bsumA, nscanN);
    scan3_k<<<nscanN, 256, 0, stream>>>(bsumA, cnt, row_ptr, dinv, N);
    // staging write + block-private CSR scatter
    write1_k<<<NBLK, 256, 0, stream>>>(ei, flag, bbase, pairs, E);
    fill3_k<<<NBUCK, 256, 0, stream>>>(pairs, bbase, tot, row_ptr, colv, N);
    prep_w_k<<<64, 256, 0, stream>>>(W1, W2, w1bf, w2bf);

    gemm1_k<<<(N + 63) / 64, 256, 0, stream>>>(x, w1bf, h1, N);
    agg1_k<<<(N + 3) / 4, 256, 0, stream>>>(h1, row_ptr, cnt, colv, dinv, b1, hr, N, E);
    gemm2_k<<<(N + 63) / 64, 256, 0, stream>>>(hr, w2bf, h2, N);
    agg2_k<<<(N + 3) / 4, 256, 0, stream>>>(h2, row_ptr, cnt, colv, dinv, b2, (float*)d_out, N, E);
}

// Round 12
// 405.784 us; speedup vs baseline: 1.4625x; 1.2799x over previous
//
#include <hip/hip_runtime.h>

// 2-layer GCN, R12: degree atomics eliminated. R11's count1 spent 133us on
// 3.2M global atomicAdd(&cnt[d]) -> 103MB cross-XCD dirty-line writeback.
// Now: count1 = bucket histogram only (LDS); degrees are computed per-bucket
// from the staged pairs by degree_k (block-private contiguous writes).
// CSR scatter stays block-private (R11's fill3, proven clean).
// Agg/GEMMs unchanged (passing, absmax 1.95e-3).

#define N_NODES 100000
#define NBLK  512   // partition blocks
#define NBUCK 391   // ceil(100000/256) buckets of 256 dst nodes

typedef __attribute__((ext_vector_type(8))) short short8;
typedef __attribute__((ext_vector_type(4))) float f32x4;

// ---------- bf16 helpers (RN-even) ----------
__device__ __forceinline__ unsigned short f2bf(float f) {
    union { float f; unsigned u; } c; c.f = f;
    unsigned r = (c.u + 0x7fffu + ((c.u >> 16) & 1u)) >> 16;
    return (unsigned short)r;
}
__device__ __forceinline__ float2 bfpair(unsigned u) {
    union { float f; unsigned u; } a, b;
    a.u = u << 16; b.u = u & 0xffff0000u;
    return make_float2(a.f, b.f);
}
__device__ __forceinline__ unsigned packbf(float a, float b) {
    return (unsigned)f2bf(a) | ((unsigned)f2bf(b) << 16);
}

// ---------- edge dtype detection (one wave) ----------
__global__ void detect64_k(const unsigned long long* __restrict__ ei, int* __restrict__ flag) {
    unsigned long long v = ei[threadIdx.x & 63];
    unsigned long long bad = __ballot(v >= (1ULL << 32));
    if (threadIdx.x == 0) *flag = (bad == 0ULL) ? 1 : 0;
}

__device__ __forceinline__ int edge_at(const void* ei, int is64, long long idx) {
    if (is64) return (int)((const long long*)ei)[idx];
    return ((const int*)ei)[idx];
}

// ---------- pass 1: per-block 391-bucket LDS histogram (NO global atomics) ----------
__global__ __launch_bounds__(256) void count1_k(const void* __restrict__ ei,
                                                const int* __restrict__ flag,
                                                int* __restrict__ bhist, int E) {
    __shared__ int lh[NBUCK];
    int t = threadIdx.x;
    for (int i = t; i < NBUCK; i += 256) lh[i] = 0;
    __syncthreads();
    int is64 = *flag;
    int C = (E + NBLK - 1) / NBLK;
    int lo = blockIdx.x * C;
    int hi = lo + C; if (hi > E) hi = E;
    for (int e = lo + t; e < hi; e += 256) {
        int d = edge_at(ei, is64, (long long)E + e);
        if ((unsigned)d < (unsigned)N_NODES) atomicAdd(&lh[d >> 8], 1);
    }
    __syncthreads();
    for (int i = t; i < NBUCK; i += 256) bhist[(size_t)i * NBLK + blockIdx.x] = lh[i];
}

// ---------- generic exclusive scan, 1024 elems/block ----------
__global__ void scan1_k(const int* __restrict__ cnt, int* __restrict__ partial,
                        int* __restrict__ bsum, int n) {
    __shared__ int sm[256];
    int t = threadIdx.x;
    int base = blockIdx.x * 1024 + t * 4;
    int v[4]; int loc = 0;
#pragma unroll
    for (int j = 0; j < 4; ++j) { v[j] = (base + j < n) ? cnt[base + j] : 0; loc += v[j]; }
    sm[t] = loc; __syncthreads();
    for (int off = 1; off < 256; off <<= 1) {
        int x = (t >= off) ? sm[t - off] : 0;
        __syncthreads();
        sm[t] += x;
        __syncthreads();
    }
    int incl = sm[t];
    int run = incl - loc;
    if (t == 255) bsum[blockIdx.x] = incl;
#pragma unroll
    for (int j = 0; j < 4; ++j) {
        if (base + j < n) partial[base + j] = run;
        run += v[j];
    }
}

__global__ void scan2_k(int* __restrict__ bsum, int nb) {
    __shared__ int sm[256];
    int t = threadIdx.x;
    int v = (t < nb) ? bsum[t] : 0;
    sm[t] = v; __syncthreads();
    for (int off = 1; off < 256; off <<= 1) {
        int x = (t >= off) ? sm[t - off] : 0;
        __syncthreads();
        sm[t] += x;
        __syncthreads();
    }
    if (t < nb) bsum[t] = sm[t] - v;
}

// finalize bucket-base scan in place; also emit total valid count
__global__ void scanadd_k(const int* __restrict__ bsum, int* __restrict__ arr,
                          const int* __restrict__ raw, int* __restrict__ tot, int n) {
    int base = blockIdx.x * 1024 + threadIdx.x * 4;
    int add = bsum[blockIdx.x];
#pragma unroll
    for (int j = 0; j < 4; ++j) {
        int i = base + j;
        if (i < n) {
            int v = arr[i] + add;
            arr[i] = v;
            if (i == n - 1) *tot = v + raw[i];
        }
    }
}

// finalize degree scan: row_ptr + dinv
__global__ void scan3_k(const int* __restrict__ bsum, const int* __restrict__ cnt,
                        int* __restrict__ row_ptr, float* __restrict__ dinv, int n) {
    int base = blockIdx.x * 1024 + threadIdx.x * 4;
    int add = bsum[blockIdx.x];
#pragma unroll
    for (int j = 0; j < 4; ++j) {
        int i = base + j;
        if (i < n) {
            row_ptr[i] += add;
            dinv[i] = rsqrtf((float)(cnt[i] + 1));  // +1 self-loop
        }
    }
}

// ---------- pass 2: deterministic staging write (src | dlocal<<17) ----------
__global__ __launch_bounds__(256) void write1_k(const void* __restrict__ ei,
                                                const int* __restrict__ flag,
                                                const int* __restrict__ bbase,
                                                unsigned* __restrict__ pairs, int E) {
    __shared__ int lofs[NBUCK];
    int t = threadIdx.x;
    for (int i = t; i < NBUCK; i += 256) lofs[i] = bbase[(size_t)i * NBLK + blockIdx.x];
    __syncthreads();
    int is64 = *flag;
    int C = (E + NBLK - 1) / NBLK;
    int lo = blockIdx.x * C;
    int hi = lo + C; if (hi > E) hi = E;
    for (int e = lo + t; e < hi; e += 256) {
        int s = edge_at(ei, is64, e);
        int d = edge_at(ei, is64, (long long)E + e);
        if ((unsigned)d >= (unsigned)N_NODES) continue;         // must match count1 filter
        if ((unsigned)s >= (unsigned)N_NODES) s = 0;            // clamp keeps counts consistent
        int b = d >> 8;
        int p = atomicAdd(&lofs[b], 1);  // LDS atomic; per-block fronts contiguous
        pairs[p] = (unsigned)s | ((unsigned)(d & 255) << 17);
    }
}

// ---------- degrees from staged pairs: one block per bucket, block-private writes ----------
__global__ __launch_bounds__(256) void degree_k(const unsigned* __restrict__ pairs,
                                                const int* __restrict__ bbase,
                                                const int* __restrict__ tot,
                                                int* __restrict__ cnt, int Nn) {
    __shared__ int lh[256];
    int b = blockIdx.x;
    int t = threadIdx.x;
    lh[t] = 0;
    __syncthreads();
    int lo = bbase[(size_t)b * NBLK];
    int hi = (b == NBUCK - 1) ? *tot : bbase[((size_t)b + 1) * NBLK];
    for (int i = lo + t; i < hi; i += 256) {
        unsigned p = __builtin_nontemporal_load(pairs + i);
        atomicAdd(&lh[p >> 17], 1);
    }
    __syncthreads();
    int n0 = b << 8;
    if (n0 + t < Nn) cnt[n0 + t] = lh[t];
}

// ---------- pass 3: block-private scatter into exact CSR positions ----------
__global__ __launch_bounds__(256) void fill3_k(const unsigned* __restrict__ pairs,
                                               const int* __restrict__ bbase,
                                               const int* __restrict__ tot,
                                               const int* __restrict__ row_ptr,
                                               int* __restrict__ colv, int Nn) {
    __shared__ int cur[256];
    int b = blockIdx.x;
    int t = threadIdx.x;
    int n0 = b << 8;
    int nn = Nn - n0; if (nn > 256) nn = 256;
    if (t < nn) cur[t] = row_ptr[n0 + t];
    __syncthreads();
    int lo = bbase[(size_t)b * NBLK];
    int hi = (b == NBUCK - 1) ? *tot : bbase[((size_t)b + 1) * NBLK];
    for (int i = lo + t; i < hi; i += 256) {
        unsigned p = __builtin_nontemporal_load(pairs + i);
        int dl = (int)(p >> 17);
        int slot = atomicAdd(&cur[dl], 1);
        colv[slot] = (int)(p & 0x1FFFFu);   // block-private ~32KB range: no line sharing
    }
}

// ---------- weight prep: W^T in bf16 ----------
__global__ void prep_w_k(const float* __restrict__ W1, const float* __restrict__ W2,
                         unsigned short* __restrict__ w1bf, unsigned short* __restrict__ w2bf) {
    int i = blockIdx.x * 256 + threadIdx.x;
    if (i < 128 * 128) { int k = i >> 7, f = i & 127; w1bf[f * 128 + k] = f2bf(W1[i]); }
    if (i < 128 * 64)  { int k = i >> 6, f = i & 63;  w2bf[f * 128 + k] = f2bf(W2[i]); }
}

// ---------- GEMM1 (MFMA): h1[n][128] bf16 node-major = x @ W1 ----------
__global__ __launch_bounds__(256) void gemm1_k(const float* __restrict__ x,
                                               const unsigned short* __restrict__ w1bf,
                                               unsigned* __restrict__ h1, int Nn) {
    __shared__ __align__(16) unsigned short sA[128][136];  // W1^T [feat][k]
    __shared__ __align__(16) unsigned short sB[64][136];   // x [node][k] bf16
    int tid = threadIdx.x;
    int n0g = blockIdx.x * 64;
    {
        const uint4* src = (const uint4*)w1bf;
#pragma unroll
        for (int l = 0; l < 8; ++l) {
            int idx = tid + l * 256;
            int f = idx >> 4, kq = idx & 15;
            *(uint4*)&sA[f][kq * 8] = src[idx];
        }
    }
    {
        int n = tid >> 2, kq = tid & 3;
        int gn = n0g + n; if (gn >= Nn) gn = Nn - 1;
        const float4* xr = (const float4*)(x + (size_t)gn * 128 + kq * 32);
        unsigned short* dst = &sB[n][kq * 32];
#pragma unroll
        for (int i = 0; i < 8; ++i) {
            float4 v = xr[i];
            dst[i * 4 + 0] = f2bf(v.x); dst[i * 4 + 1] = f2bf(v.y);
            dst[i * 4 + 2] = f2bf(v.z); dst[i * 4 + 3] = f2bf(v.w);
        }
    }
    __syncthreads();
    int wave = tid >> 6, lane = tid & 63;
    int quad = lane >> 4, l16 = lane & 15;
    f32x4 z = {0.f, 0.f, 0.f, 0.f};
    f32x4 acc[8];
#pragma unroll
    for (int t = 0; t < 8; ++t) acc[t] = z;
#pragma unroll
    for (int kk = 0; kk < 4; ++kk) {
        int kb = kk * 32 + quad * 8;
        short8 a = *(const short8*)&sB[wave * 16 + l16][kb];
#pragma unroll
        for (int ft = 0; ft < 8; ++ft) {
            short8 b = *(const short8*)&sA[ft * 16 + l16][kb];
            acc[ft] = __builtin_amdgcn_mfma_f32_16x16x32_bf16(a, b, acc[ft], 0, 0, 0);
        }
    }
    __syncthreads();  // reuse sA as transpose buffer
    unsigned short (*sC)[136] = sA;
#pragma unroll
    for (int ft = 0; ft < 8; ++ft)
#pragma unroll
        for (int r = 0; r < 4; ++r)
            sC[wave * 16 + quad * 4 + r][ft * 16 + l16] = f2bf(acc[ft][r]);
    __syncthreads();
#pragma unroll
    for (int l = 0; l < 4; ++l) {
        int idx = tid + l * 256;
        int row = idx >> 4, q = idx & 15;
        int gn = n0g + row;
        if (gn < Nn)
            *(uint4*)&h1[(size_t)gn * 64 + q * 4] = *(uint4*)&sC[row][q * 8];
    }
}

// ---------- GEMM2 (MFMA): h2[n][64] bf16 node-major = hr @ W2 ----------
__global__ __launch_bounds__(256) void gemm2_k(const unsigned* __restrict__ hr,
                                               const unsigned short* __restrict__ w2bf,
                                               unsigned* __restrict__ h2, int Nn) {
    __shared__ __align__(16) unsigned short sA[64][136];
    __shared__ __align__(16) unsigned short sB[64][136];
    int tid = threadIdx.x;
    int n0g = blockIdx.x * 64;
    {
        const uint4* src = (const uint4*)w2bf;
#pragma unroll
        for (int l = 0; l < 4; ++l) {
            int idx = tid + l * 256;
            int f = idx >> 4, kq = idx & 15;
            *(uint4*)&sA[f][kq * 8] = src[idx];
        }
    }
    {
        const uint4* src = (const uint4*)hr;
#pragma unroll
        for (int l = 0; l < 4; ++l) {
            int idx = tid + l * 256;
            int row = idx >> 4, q = idx & 15;
            int gn = n0g + row; if (gn >= Nn) gn = Nn - 1;
            *(uint4*)&sB[row][q * 8] = src[(size_t)gn * 16 + q];
        }
    }
    __syncthreads();
    int wave = tid >> 6, lane = tid & 63;
    int quad = lane >> 4, l16 = lane & 15;
    f32x4 z = {0.f, 0.f, 0.f, 0.f};
    f32x4 acc[4];
#pragma unroll
    for (int t = 0; t < 4; ++t) acc[t] = z;
#pragma unroll
    for (int kk = 0; kk < 4; ++kk) {
        int kb = kk * 32 + quad * 8;
        short8 a = *(const short8*)&sB[wave * 16 + l16][kb];
#pragma unroll
        for (int ft = 0; ft < 4; ++ft) {
            short8 b = *(const short8*)&sA[ft * 16 + l16][kb];
            acc[ft] = __builtin_amdgcn_mfma_f32_16x16x32_bf16(a, b, acc[ft], 0, 0, 0);
        }
    }
    __syncthreads();
    unsigned short (*sC)[136] = sA;
#pragma unroll
    for (int ft = 0; ft < 4; ++ft)
#pragma unroll
        for (int r = 0; r < 4; ++r)
            sC[wave * 16 + quad * 4 + r][ft * 16 + l16] = f2bf(acc[ft][r]);
    __syncthreads();
#pragma unroll
    for (int l = 0; l < 2; ++l) {
        int idx = tid + l * 256;
        int row = idx >> 3, q = idx & 7;
        int gn = n0g + row;
        if (gn < Nn)
            *(uint4*)&h2[(size_t)gn * 32 + q * 4] = *(uint4*)&sC[row][q * 8];
    }
}

// ---------- agg1: wave=node, batched colv/dinv + shfl, 4-deep row-gather MLP ----------
__global__ __launch_bounds__(256) void agg1_k(const unsigned* __restrict__ h,
                                              const int* __restrict__ row_ptr,
                                              const int* __restrict__ cnt,
                                              const int* __restrict__ colv,
                                              const float* __restrict__ dinv,
                                              const float* __restrict__ bias,
                                              unsigned* __restrict__ out, int Nn, int E) {
    int node = blockIdx.x * 4 + (threadIdx.x >> 6);
    if (node >= Nn) return;
    int lane = threadIdx.x & 63;
    float di = dinv[node];
    int start = row_ptr[node];
    int deg = cnt[node];

    float2 hv = bfpair(h[(size_t)node * 64 + lane]);
    float w0 = di * di;
    float ax = w0 * hv.x, ay = w0 * hv.y;

    for (int base = 0; base < deg; base += 64) {
        int idx = base + lane;
        int ci = start + idx; if (ci >= E) ci = E - 1;
        int sl = colv[ci];
        float wl = (idx < deg) ? dinv[sl] : 0.f;
        int m = deg - base; if (m > 64) m = 64;
        int j = 0;
        for (; j + 4 <= m; j += 4) {
            int s0 = __shfl(sl, j),     s1 = __shfl(sl, j + 1);
            int s2 = __shfl(sl, j + 2), s3 = __shfl(sl, j + 3);
            float e0 = di * __shfl(wl, j),     e1 = di * __shfl(wl, j + 1);
            float e2 = di * __shfl(wl, j + 2), e3 = di * __shfl(wl, j + 3);
            unsigned u0 = h[(size_t)s0 * 64 + lane];
            unsigned u1 = h[(size_t)s1 * 64 + lane];
            unsigned u2 = h[(size_t)s2 * 64 + lane];
            unsigned u3 = h[(size_t)s3 * 64 + lane];
            float2 v0 = bfpair(u0), v1 = bfpair(u1), v2 = bfpair(u2), v3 = bfpair(u3);
            ax = fmaf(e0, v0.x, ax); ay = fmaf(e0, v0.y, ay);
            ax = fmaf(e1, v1.x, ax); ay = fmaf(e1, v1.y, ay);
            ax = fmaf(e2, v2.x, ax); ay = fmaf(e2, v2.y, ay);
            ax = fmaf(e3, v3.x, ax); ay = fmaf(e3, v3.y, ay);
        }
        for (; j < m; ++j) {
            int s = __shfl(sl, j);
            float we = di * __shfl(wl, j);
            float2 v = bfpair(h[(size_t)s * 64 + lane]);
            ax = fmaf(we, v.x, ax); ay = fmaf(we, v.y, ay);
        }
    }
    float r0 = fmaxf(ax + bias[lane * 2], 0.f);
    float r1 = fmaxf(ay + bias[lane * 2 + 1], 0.f);
    out[(size_t)node * 64 + lane] = packbf(r0, r1);
}

// ---------- agg2: wave=node, 2 edges per gather instruction ----------
__global__ __launch_bounds__(256) void agg2_k(const unsigned* __restrict__ h,
                                              const int* __restrict__ row_ptr,
                                              const int* __restrict__ cnt,
                                              const int* __restrict__ colv,
                                              const float* __restrict__ dinv,
                                              const float* __restrict__ bias,
                                              float* __restrict__ out, int Nn, int E) {
    int node = blockIdx.x * 4 + (threadIdx.x >> 6);
    if (node >= Nn) return;
    int lane = threadIdx.x & 63;
    int half = lane >> 5, fp = lane & 31;
    float di = dinv[node];
    int start = row_ptr[node];
    int deg = cnt[node];

    float2 hv = bfpair(h[(size_t)node * 32 + fp]);
    float w0 = (half == 0) ? di * di : 0.f;
    float ax = w0 * hv.x, ay = w0 * hv.y;

    for (int base = 0; base < deg; base += 64) {
        int idx = base + lane;
        int ci = start + idx; if (ci >= E) ci = E - 1;
        int sl = colv[ci];
        float wl = (idx < deg) ? dinv[sl] : 0.f;
        int m = deg - base; if (m > 64) m = 64;
        int j = 0;
        for (; j + 8 <= m; j += 8) {
            int q0 = j + half, q1 = j + 2 + half, q2 = j + 4 + half, q3 = j + 6 + half;
            int s0 = __shfl(sl, q0), s1 = __shfl(sl, q1);
            int s2 = __shfl(sl, q2), s3 = __shfl(sl, q3);
            float e0 = di * __shfl(wl, q0), e1 = di * __shfl(wl, q1);
            float e2 = di * __shfl(wl, q2), e3 = di * __shfl(wl, q3);
            unsigned u0 = h[(size_t)s0 * 32 + fp];
            unsigned u1 = h[(size_t)s1 * 32 + fp];
            unsigned u2 = h[(size_t)s2 * 32 + fp];
            unsigned u3 = h[(size_t)s3 * 32 + fp];
            float2 v0 = bfpair(u0), v1 = bfpair(u1), v2 = bfpair(u2), v3 = bfpair(u3);
            ax = fmaf(e0, v0.x, ax); ay = fmaf(e0, v0.y, ay);
            ax = fmaf(e1, v1.x, ax); ay = fmaf(e1, v1.y, ay);
            ax = fmaf(e2, v2.x, ax); ay = fmaf(e2, v2.y, ay);
            ax = fmaf(e3, v3.x, ax); ay = fmaf(e3, v3.y, ay);
        }
        for (; j < m; j += 2) {
            int q = j + half;
            int s = __shfl(sl, q & 63);
            float we = di * __shfl(wl, q & 63);
            float2 v = bfpair(h[(size_t)s * 32 + fp]);
            ax = fmaf(we, v.x, ax); ay = fmaf(we, v.y, ay);
        }
    }
    ax += __shfl_xor(ax, 32, 64);
    ay += __shfl_xor(ay, 32, 64);
    if (half == 0) {
        float2 r = make_float2(ax + bias[fp * 2], ay + bias[fp * 2 + 1]);
        *(float2*)&out[(size_t)node * 64 + fp * 2] = r;
    }
}

// ---------- launch ----------
extern "C" void kernel_launch(void* const* d_in, const int* in_sizes, int n_in,
                              void* d_out, int out_size, void* d_ws, size_t ws_size,
                              hipStream_t stream) {
    const float* x  = (const float*)d_in[0];
    const void*  ei = d_in[1];
    const float* W1 = (const float*)d_in[2];
    const float* b1 = (const float*)d_in[3];
    const float* W2 = (const float*)d_in[4];
    const float* b2 = (const float*)d_in[5];

    const int N = N_NODES;
    const int E = in_sizes[1] / 2;
    const int NB = NBLK * NBUCK;  // 200192

    char* w = (char*)d_ws;
    size_t off = 0;
    auto take = [&](size_t bytes) {
        void* p = w + off;
        off = (off + bytes + 255) & ~(size_t)255;
        return p;
    };
    int*   flag    = (int*)take(2 * sizeof(int));
    int*   tot     = flag + 1;
    int*   cnt     = (int*)take((size_t)N * 4);
    int*   row_ptr = (int*)take((size_t)N * 4);
    int*   bsumA   = (int*)take(256 * 4);
    int*   bsumB   = (int*)take(256 * 4);
    int*   bhist   = (int*)take((size_t)NB * 4);
    int*   bbase   = (int*)take((size_t)NB * 4);
    float* dinv    = (float*)take((size_t)N * 4);
    unsigned* pairs = (unsigned*)take((size_t)E * 4);
    int*   colv    = (int*)take((size_t)E * 4);
    unsigned short* w1bf = (unsigned short*)take(128 * 128 * 2);
    unsigned short* w2bf = (unsigned short*)take(64 * 128 * 2);
    unsigned* hr   = (unsigned*)take((size_t)N * 64 * 4);   // bf16 [N][128]
    unsigned* h2   = (unsigned*)take((size_t)N * 32 * 4);   // bf16 [N][64]
    (void)ws_size; (void)n_in; (void)out_size;

    unsigned* h1 = (unsigned*)d_out;  // bf16 [N][128] in d_out, dead before agg2 writes

    const int nscanN = (N + 1023) / 1024;   // 98
    const int nscanB = (NB + 1023) / 1024;  // 196

    detect64_k<<<1, 64, 0, stream>>>((const unsigned long long*)ei, flag);
    count1_k<<<NBLK, 256, 0, stream>>>(ei, flag, bhist, E);
    // bucket-base scan (exclusive over bucket-major [NBUCK][NBLK])
    scan1_k<<<nscanB, 256, 0, stream>>>(bhist, bbase, bsumB, NB);
    scan2_k<<<1, 256, 0, stream>>>(bsumB, nscanB);
    scanadd_k<<<nscanB, 256, 0, stream>>>(bsumB, bbase, bhist, tot, NB);
    // stage pairs, then block-private degrees
    write1_k<<<NBLK, 256, 0, stream>>>(ei, flag, bbase, pairs, E);
    degree_k<<<NBUCK, 256, 0, stream>>>(pairs, bbase, tot, cnt, N);
    // degree scan -> row_ptr, dinv
    scan1_k<<<nscanN, 256, 0, stream>>>(cnt, row_ptr, bsumA, N);
    scan2_k<<<1, 256, 0, stream>>>(bsumA, nscanN);
    scan3_k<<<nscanN, 256, 0, stream>>>(bsumA, cnt, row_ptr, dinv, N);
    // block-private CSR scatter
    fill3_k<<<NBUCK, 256, 0, stream>>>(pairs, bbase, tot, row_ptr, colv, N);
    prep_w_k<<<64, 256, 0, stream>>>(W1, W2, w1bf, w2bf);

    gemm1_k<<<(N + 63) / 64, 256, 0, stream>>>(x, w1bf, h1, N);
    agg1_k<<<(N + 3) / 4, 256, 0, stream>>>(h1, row_ptr, cnt, colv, dinv, b1, hr, N, E);
    gemm2_k<<<(N + 63) / 64, 256, 0, stream>>>(hr, w2bf, h2, N);
    agg2_k<<<(N + 3) / 4, 256, 0, stream>>>(h2, row_ptr, cnt, colv, dinv, b2, (float*)d_out, N, E);
}